// Round 9
// baseline (56.055 us; speedup 1.0000x reference)
//
#include <hip/hip_runtime.h>

// inputs (B=64, N=128, N=128, L=16) f32; w (L,6,F=32) [l*192 + op*32 + f]; bias/diag_bias (F,)
#define NN 128
#define LL 16
#define FF 32

typedef float vf4 __attribute__((ext_vector_type(4)));

// Single dispatch: 256 blocks x 1024 threads (16 waves = 4/SIMD), 1 block/CU.
// Block -> (batch b, quarter m): owns rows m*32..m*32+31 of batch b.
// Swizzle co-locates the 4 blocks of a batch on one XCD (phys%8 == b%8) so
// their 4x redundant 1MB batch reads are L2-served (r8 counters: FETCH = 1x input).
__global__ __launch_bounds__(1024, 4) void k_one(const float* __restrict__ in,
                                                 const float* __restrict__ w,
                                                 const float* __restrict__ bias,
                                                 const float* __restrict__ dbias,
                                                 float* __restrict__ out) {
    __shared__ __align__(16) float sRS[NN][20];      // batch rowsums, stride 20 (b128-aligned)
    __shared__ __align__(16) float sIn[4][NN * 20];  // 4 staged rows, stride 20 -> conflict-free
    __shared__ float sTSp[8][16];
    __shared__ float sTS[16];
    __shared__ __align__(16) float sA[32][FF], sD[32][FF];

    const int phys = blockIdx.x;            // 0..255
    const int xcd  = phys & 7;
    const int seq  = phys >> 3;             // 0..31
    const int m    = seq & 3;               // quarter (which 32 rows)
    const int b    = (seq >> 2) * 8 + xcd;  // batch 0..63 (bijective)
    const int t    = threadIdx.x;           // 0..1023
    const int lane = t & 63;
    const int wv   = t >> 6;                // wave 0..15
    const int g8   = t & 7;                 // f-quad
    const int p    = (t >> 3) & 31;         // pixel lane
    const float invN  = 1.f / 50.f;
    const float invN2 = 1.f / 2500.f;

    const vf4* bin = reinterpret_cast<const vf4*>(in) + (size_t)b * (NN * 512);  // 65536 f4

    // ---- phase A: rowsums of the whole batch (one wave per row, 8 sweeps) ----
#pragma unroll
    for (int rr = 0; rr < 8; ++rr) {
        const int row = rr * 16 + wv;
        const vf4* src = bin + row * 512;
        float ax = 0.f, ay = 0.f, az = 0.f, aw = 0.f;
#pragma unroll
        for (int k = 0; k < 8; ++k) {
            const vf4 v = src[k * 64 + lane];
            ax += v.x; ay += v.y; az += v.z; aw += v.w;
        }
#pragma unroll
        for (int s = 4; s < 64; s <<= 1) {
            ax += __shfl_xor(ax, s); ay += __shfl_xor(ay, s);
            az += __shfl_xor(az, s); aw += __shfl_xor(aw, s);
        }
        if (lane < 4) {  // lane == lq holds sum for l = lane*4..+3
            vf4 o; o.x = ax; o.y = ay; o.z = az; o.w = aw;
            *reinterpret_cast<vf4*>(&sRS[row][lane * 4]) = o;
        }
    }
    __syncthreads();

    // ---- totsum (raw) ----
    if (t < 128) {
        const int l = t & 15, c = t >> 4;
        float s = 0.f;
#pragma unroll
        for (int ii = 0; ii < 16; ++ii) s += sRS[c * 16 + ii][l];
        sTSp[c][l] = s;
    }
    __syncthreads();
    if (t < 16) {
        float s = 0.f;
#pragma unroll
        for (int c = 0; c < 8; ++c) s += sTSp[c][t];
        sTS[t] = s;
    }
    __syncthreads();

    // ---- A/D for this block's 32 rows (1024 tasks, 1/thread) ----
    {
        const int c = t >> 5, f = t & 31;            // local row c, feature f
        const int rowLocal = m * 32 + c;             // batch-local row
        float dA = 0.f, tA = 0.f, dD = 0.f, tD = 0.f;
#pragma unroll
        for (int l = 0; l < LL; ++l) {
            const float rv = sRS[rowLocal][l];
            const float ts = sTS[l];
            dA = fmaf(rv, w[l * 192 +  64 + f], dA);   // op2
            dD = fmaf(rv, w[l * 192 + 128 + f], dD);   // op4
            tA = fmaf(ts, w[l * 192 +  32 + f], tA);   // op1
            tD = fmaf(ts, w[l * 192 + 160 + f], tD);   // op5
        }
        sA[c][f] = dA * invN + tA * invN2 + bias[f];
        sD[c][f] = dD * invN + tD * invN2 + dbias[f];
    }

    // ---- C quads (op3) for this thread's 4 j-columns, in registers ----
    float c4x[4] = {0.f, 0.f, 0.f, 0.f};
    float c4y[4] = {0.f, 0.f, 0.f, 0.f};
    float c4z[4] = {0.f, 0.f, 0.f, 0.f};
    float c4w[4] = {0.f, 0.f, 0.f, 0.f};
#pragma unroll
    for (int lq = 0; lq < 4; ++lq) {
        float4 w3q[4];
#pragma unroll
        for (int e = 0; e < 4; ++e)
            w3q[e] = *reinterpret_cast<const float4*>(w + (lq * 4 + e) * 192 + 96 + g8 * 4);
#pragma unroll
        for (int it = 0; it < 4; ++it) {
            const vf4 rv = *reinterpret_cast<const vf4*>(&sRS[p + 32 * it][lq * 4]);
#pragma unroll
            for (int e = 0; e < 4; ++e) {
                const float r = (e == 0) ? rv.x : (e == 1) ? rv.y : (e == 2) ? rv.z : rv.w;
                c4x[it] = fmaf(r, w3q[e].x, c4x[it]);
                c4y[it] = fmaf(r, w3q[e].y, c4y[it]);
                c4z[it] = fmaf(r, w3q[e].z, c4z[it]);
                c4w[it] = fmaf(r, w3q[e].w, c4w[it]);
            }
        }
    }
#pragma unroll
    for (int it = 0; it < 4; ++it) {
        c4x[it] *= invN; c4y[it] *= invN; c4z[it] *= invN; c4w[it] *= invN;
    }

    // ---- w0 column quads in registers ----
    float4 w0r[LL];
#pragma unroll
    for (int l = 0; l < LL; ++l)
        w0r[l] = *reinterpret_cast<const float4*>(w + l * 192 + g8 * 4);
    __syncthreads();   // sA/sD ready; sRS reads done

    // ---- phase B: 8 iterations of 4 rows over this block's 32 rows ----
    const int r4 = t >> 8;   // which of the 4 staged rows this thread computes (const per wave)
#pragma unroll 1
    for (int cc = 0; cc < 8; ++cc) {
        const int gr0 = m * 32 + cc * 4;   // batch-local row of group base
        // stage 4 rows (2048 f4, coalesced; L2-hot from phase A)
        const vf4* rb = bin + (size_t)gr0 * 512;
#pragma unroll
        for (int k = 0; k < 2; ++k) {
            const int v  = k * 1024 + t;
            const int r  = v >> 9;          // row in group
            const int vv = v & 511;
            *reinterpret_cast<vf4*>(&sIn[r][(vv >> 2) * 20 + (vv & 3) * 4]) = rb[v];
        }
        __syncthreads();

        const int lr = cc * 4 + r4;        // local row 0..31
        const int gr = m * 32 + lr;        // batch-local row
        const float4 A4 = *reinterpret_cast<const float4*>(&sA[lr][g8 * 4]);
        const float4 D4 = *reinterpret_cast<const float4*>(&sD[lr][g8 * 4]);

#pragma unroll
        for (int it = 0; it < 4; ++it) {
            const int j = p + 32 * it;
            float in_l[LL];
#pragma unroll
            for (int lq = 0; lq < 4; ++lq) {
                const vf4 d = *reinterpret_cast<const vf4*>(&sIn[r4][j * 20 + lq * 4]);
                in_l[lq * 4 + 0] = d.x; in_l[lq * 4 + 1] = d.y;
                in_l[lq * 4 + 2] = d.z; in_l[lq * 4 + 3] = d.w;
            }
            float a0 = A4.x + c4x[it];
            float a1 = A4.y + c4y[it];
            float a2 = A4.z + c4z[it];
            float a3 = A4.w + c4w[it];
            if (j == gr) { a0 += D4.x; a1 += D4.y; a2 += D4.z; a3 += D4.w; }
#pragma unroll
            for (int l = 0; l < LL; ++l) {
                a0 = fmaf(in_l[l], w0r[l].x, a0);
                a1 = fmaf(in_l[l], w0r[l].y, a1);
                a2 = fmaf(in_l[l], w0r[l].z, a2);
                a3 = fmaf(in_l[l], w0r[l].w, a3);
            }
            vf4 o;
            o.x = fmaxf(a0, 0.f); o.y = fmaxf(a1, 0.f);
            o.z = fmaxf(a2, 0.f); o.w = fmaxf(a3, 0.f);
            float* dst = out + (((size_t)b * NN + gr) * NN + j) * FF + g8 * 4;
            __builtin_nontemporal_store(o, reinterpret_cast<vf4*>(dst));  // never re-read
        }
        __syncthreads();   // sIn free for next group
    }
}

extern "C" void kernel_launch(void* const* d_in, const int* in_sizes, int n_in,
                              void* d_out, int out_size, void* d_ws, size_t ws_size,
                              hipStream_t stream) {
    const float* in    = (const float*)d_in[0];  // (64,128,128,16)
    const float* w     = (const float*)d_in[1];  // (16,6,32)
    const float* bias  = (const float*)d_in[2];  // (32,)
    const float* dbias = (const float*)d_in[3];  // (32,)
    float* out = (float*)d_out;

    hipLaunchKernelGGL(k_one, dim3(256), dim3(1024), 0, stream,
                       in, w, bias, dbias, out);
}